// Round 1
// baseline (2354.860 us; speedup 1.0000x reference)
//
#include <hip/hip_runtime.h>
#include <hip/hip_bf16.h>
#include <math.h>

#define D_R 333
#define D_IN 333
#define NB 4096

// ---------------- Kernel A1: raw attention logits -> sigmoid, one wave per region ----------------
__global__ __launch_bounds__(256) void att_raw_kernel(const float* __restrict__ r_id,
                                                      const float* __restrict__ att_w,
                                                      float* __restrict__ ws_raw) {
    int tid  = threadIdx.x;
    int lane = tid & 63;
    int wave = tid >> 6;
    int r = blockIdx.x * 4 + wave;
    if (r >= D_R) return;
    const float* row = r_id + (size_t)r * D_R;
    float acc = 0.f;
    for (int c = lane; c < D_R; c += 64) acc += row[c] * att_w[c];
    #pragma unroll
    for (int off = 32; off > 0; off >>= 1) acc += __shfl_down(acc, off, 64);
    if (lane == 0) ws_raw[r] = 1.f / (1.f + expf(-acc));
}

// ---------------- Kernel A2: normalize attention, write r_att output + ws ----------------
__global__ __launch_bounds__(384) void att_norm_kernel(const float* __restrict__ ws_raw,
                                                       float* __restrict__ r_att_out,
                                                       float* __restrict__ ws_norm) {
    __shared__ float s_val[384];
    __shared__ float s_part[6];
    __shared__ float s_sum;
    int tid = threadIdx.x;
    float v = (tid < D_R) ? ws_raw[tid] : 0.f;
    s_val[tid] = v;
    // wave reduce
    float acc = v;
    #pragma unroll
    for (int off = 32; off > 0; off >>= 1) acc += __shfl_down(acc, off, 64);
    int lane = tid & 63, wave = tid >> 6;
    if (lane == 0) s_part[wave] = acc;
    __syncthreads();
    if (tid == 0) {
        float s = 0.f;
        #pragma unroll
        for (int i = 0; i < 6; ++i) s += s_part[i];
        s_sum = s + 1e-8f;
    }
    __syncthreads();
    if (tid < D_R) {
        float a = s_val[tid] / s_sum;
        r_att_out[tid] = a;
        ws_norm[tid]   = a;
    }
}

// ---------------- Kernel B: fused batched GEMV, one wave per (b, r) row ----------------
__global__ __launch_bounds__(256) void gemv_kernel(const float* __restrict__ x,
                                                   const float* __restrict__ W,
                                                   const float* __restrict__ bias,
                                                   float* __restrict__ r_out,
                                                   int total_rows) {
    int tid  = threadIdx.x;
    int lane = tid & 63;
    int wave = tid >> 6;
    int row = blockIdx.x * 4 + wave;
    if (row >= total_rows) return;
    int b = row / D_R;                // compiler magic-mul
    int r = row - b * D_R;
    const float* xrow = x + (size_t)row * D_IN;
    const float* wrow = W + (size_t)r * D_IN;
    float acc = 0.f;
    #pragma unroll
    for (int k = 0; k < 5; ++k) {
        int d = lane + k * 64;        // max 319 < 333, always valid
        acc += xrow[d] * wrow[d];
    }
    {
        int d = lane + 320;
        if (d < D_IN) acc += xrow[d] * wrow[d];
    }
    #pragma unroll
    for (int off = 32; off > 0; off >>= 1) acc += __shfl_down(acc, off, 64);
    if (lane == 0) r_out[row] = acc + bias[r];
}

// ---------------- Kernel C: attention-weighted reduce over regions, one wave per batch ----------------
__global__ __launch_bounds__(256) void out_kernel(const float* __restrict__ r_out,
                                                  const float* __restrict__ r_att,
                                                  float* __restrict__ out) {
    __shared__ float s_att[D_R];
    int tid = threadIdx.x;
    for (int i = tid; i < D_R; i += 256) s_att[i] = r_att[i];
    __syncthreads();
    int lane = tid & 63;
    int wave = tid >> 6;
    int b = blockIdx.x * 4 + wave;
    if (b >= NB) return;
    const float* row = r_out + (size_t)b * D_R;
    float acc = 0.f;
    for (int r = lane; r < D_R; r += 64) acc += row[r] * s_att[r];
    #pragma unroll
    for (int off = 32; off > 0; off >>= 1) acc += __shfl_down(acc, off, 64);
    if (lane == 0) out[b] = acc;
}

extern "C" void kernel_launch(void* const* d_in, const int* in_sizes, int n_in,
                              void* d_out, int out_size, void* d_ws, size_t ws_size,
                              hipStream_t stream) {
    const float* x     = (const float*)d_in[0];
    const float* r_id  = (const float*)d_in[1];
    const float* W     = (const float*)d_in[2];
    const float* bias  = (const float*)d_in[3];
    const float* att_w = (const float*)d_in[4];

    float* out_f   = (float*)d_out;                 // [4096]
    float* r_out_f = out_f + NB;                    // [4096*333]
    float* r_att_f = out_f + NB + (size_t)NB * D_R; // [333]

    float* ws_raw  = (float*)d_ws;        // 333 floats: raw sigmoids
    float* ws_norm = ws_raw + 512;        // 333 floats: normalized attention

    // A1: raw sigmoid attention (one wave per region)
    att_raw_kernel<<<(D_R + 3) / 4, 256, 0, stream>>>(r_id, att_w, ws_raw);
    // A2: normalize + emit r_att
    att_norm_kernel<<<1, 384, 0, stream>>>(ws_raw, r_att_f, ws_norm);
    // B: main batched GEMV (one wave per row)
    int total_rows = NB * D_R;
    gemv_kernel<<<(total_rows + 3) / 4, 256, 0, stream>>>(x, W, bias, r_out_f, total_rows);
    // C: weighted reduce -> out
    out_kernel<<<(NB + 3) / 4, 256, 0, stream>>>(r_out_f, ws_norm, out_f);
}